// Round 1
// baseline (443.802 us; speedup 1.0000x reference)
//
#include <hip/hip_runtime.h>

#define ND 64
#define NPAIR 6

typedef short bf16x8 __attribute__((ext_vector_type(8)));
typedef float floatx4 __attribute__((ext_vector_type(4)));

static constexpr int SPB  = 16;            // samples per block
static constexpr int ROWS = SPB * NPAIR;   // 96 M-rows per block
static constexpr int ASTR = 200;           // halfwords per A row (192 + 8 pad; 400B, 16B-aligned, bank-spread)
static constexpr int DSTR = 72;            // halfwords per D0 row (64 + 8 pad)

__device__ __forceinline__ unsigned short f2bf(float f) {
    unsigned u = __builtin_bit_cast(unsigned, f);
    u += 0x7FFFu + ((u >> 16) & 1u);       // round-to-nearest-even (no NaN inputs)
    return (unsigned short)(u >> 16);
}
__device__ __forceinline__ unsigned f2bf2(float lo, float hi) {
    return (unsigned)f2bf(lo) | ((unsigned)f2bf(hi) << 16);
}
__device__ __forceinline__ float bf2f(unsigned short h) {
    unsigned u = ((unsigned)h) << 16;
    return __builtin_bit_cast(float, u);
}

// Repack W1..3 [o][i][k] fp32 -> bf16 B-operand layout P[L][n=o][j], j<128: (i=j>>1,k=j&1), j>=128: (i=j-128,k=2)
__global__ void repack_w(const float* __restrict__ W1, const float* __restrict__ W2,
                         const float* __restrict__ W3, unsigned short* __restrict__ P) {
    int idx = blockIdx.x * 256 + threadIdx.x;
    if (idx >= 3 * 64 * 192) return;
    int j = idx % 192;
    int n = (idx / 192) % 64;
    int L = idx / (192 * 64);
    const float* W = (L == 0) ? W1 : (L == 1) ? W2 : W3;
    float v = (j < 128) ? W[n * 192 + (j >> 1) * 3 + (j & 1)]
                        : W[n * 192 + (j - 128) * 3 + 2];
    P[idx] = f2bf(v);
}

__global__ __launch_bounds__(256, 3) void dijet_main(
    const float* __restrict__ x, const float* __restrict__ d,
    const float* __restrict__ b1, const float* __restrict__ b2,
    const float* __restrict__ b3, const unsigned short* __restrict__ Wp,
    float* __restrict__ out)
{
    __shared__ unsigned short A[ROWS * ASTR];   // 38400 B: [row][j]  j<128 x-part, j>=128 d-part (updated per layer)
    __shared__ unsigned short D0[ROWS * DSTR];  // 13824 B: residual copy of initial d

    const int t  = threadIdx.x;
    const int b0 = blockIdx.x * SPB;

    // ---- stage x: 16 samples x 768 floats = 3072 float4; coalesced; convert + scatter to A x-part
    {
        const float4* x4 = (const float4*)(x + (size_t)b0 * (ND * 12));
        unsigned* A32 = (unsigned*)A;
        #pragma unroll
        for (int m = 0; m < 12; ++m) {
            int idx = m * 256 + t;             // 0..3071
            float4 v = x4[idx];
            int b   = idx / 192;               // 192 float4 per sample
            int rem = idx - b * 192;
            int i   = rem / 3;                 // channel
            int c0  = (rem - i * 3) * 4;       // 0,4,8
            int row0 = b * 6 + (c0 >> 1);      // slot = c/2
            A32[row0 * (ASTR / 2) + i]       = f2bf2(v.x, v.y);  // j = 2i, 2i+1
            A32[(row0 + 1) * (ASTR / 2) + i] = f2bf2(v.z, v.w);
        }
    }
    // ---- stage d: 16 samples x 384 floats = 3072 float2; each float2 = same i, slots (s,s+1)
    {
        const float2* d2 = (const float2*)(d + (size_t)b0 * (ND * NPAIR));
        #pragma unroll
        for (int m = 0; m < 12; ++m) {
            int idx = m * 256 + t;             // 0..3071
            float2 v = d2[idx];
            int e   = idx * 2;
            int b   = e / 384;
            int rem = e - b * 384;
            int i   = rem / 6;
            int s   = rem - i * 6;             // even
            int row = b * 6 + s;
            unsigned short lo = f2bf(v.x), hi = f2bf(v.y);
            A[row * ASTR + 128 + i]       = lo;
            A[(row + 1) * ASTR + 128 + i] = hi;
            D0[row * DSTR + i]            = lo;
            D0[(row + 1) * DSTR + i]      = hi;
        }
    }
    __syncthreads();

    const int wave = t >> 6;
    const int lane = t & 63;
    const int mhalf = wave & 1;                // row half (48 rows)
    const int nhalf = wave >> 1;               // col half (32 cols)
    const int l15  = lane & 15;
    const int quad = lane >> 4;

    const int mbase = mhalf * 48;
    const int nbase = nhalf * 32;

    #pragma unroll
    for (int L = 0; L < 3; ++L) {
        const float* bL = (L == 0) ? b1 : (L == 1) ? b2 : b3;
        const unsigned short* WL = Wp + L * (64 * 192);

        // B fragments for this wave's col half: 2 n-tiles x 6 k-steps, from L2-resident packed weights
        bf16x8 Bf[2][6];
        #pragma unroll
        for (int nt = 0; nt < 2; ++nt)
            #pragma unroll
            for (int kk = 0; kk < 6; ++kk)
                Bf[nt][kk] = *(const bf16x8*)(WL + (nbase + nt * 16 + l15) * 192 + kk * 32 + quad * 8);
        float bias0 = bL[nbase + l15];
        float bias1 = bL[nbase + 16 + l15];

        floatx4 acc[3][2] = {};
        #pragma unroll
        for (int kk = 0; kk < 6; ++kk) {
            #pragma unroll
            for (int mt = 0; mt < 3; ++mt) {
                bf16x8 Af = *(const bf16x8*)(A + (mbase + mt * 16 + l15) * ASTR + kk * 32 + quad * 8);
                acc[mt][0] = __builtin_amdgcn_mfma_f32_16x16x32_bf16(Af, Bf[0][kk], acc[mt][0], 0, 0, 0);
                acc[mt][1] = __builtin_amdgcn_mfma_f32_16x16x32_bf16(Af, Bf[1][kk], acc[mt][1], 0, 0, 0);
            }
        }

        if (L < 2) {
            __syncthreads();   // everyone done reading old d-part
            #pragma unroll
            for (int mt = 0; mt < 3; ++mt) {
                #pragma unroll
                for (int nt = 0; nt < 2; ++nt) {
                    float bias = nt ? bias1 : bias0;
                    int o = nbase + nt * 16 + l15;
                    #pragma unroll
                    for (int r = 0; r < 4; ++r) {
                        int row = mbase + mt * 16 + quad * 4 + r;   // C/D: col=lane&15, row=quad*4+reg
                        float v = acc[mt][nt][r] + bias;
                        v = v > 0.f ? v : 0.f;
                        A[row * ASTR + 128 + o] = f2bf(v);
                    }
                }
            }
            __syncthreads();   // new d visible before next layer's reads
        } else {
            #pragma unroll
            for (int mt = 0; mt < 3; ++mt) {
                #pragma unroll
                for (int nt = 0; nt < 2; ++nt) {
                    float bias = nt ? bias1 : bias0;
                    int o = nbase + nt * 16 + l15;
                    #pragma unroll
                    for (int r = 0; r < 4; ++r) {
                        int row = mbase + mt * 16 + quad * 4 + r;
                        float v = acc[mt][nt][r] + bias + bf2f(D0[row * DSTR + o]);
                        v = v > 0.f ? v : 0.f;
                        int bl = row / 6;
                        int s  = row - bl * 6;
                        out[(size_t)(b0 + bl) * (ND * NPAIR) + o * 6 + s] = v;
                    }
                }
            }
        }
    }
}

extern "C" void kernel_launch(void* const* d_in, const int* in_sizes, int n_in,
                              void* d_out, int out_size, void* d_ws, size_t ws_size,
                              hipStream_t stream)
{
    const float* x  = (const float*)d_in[0];
    const float* dd = (const float*)d_in[1];
    const float* W1 = (const float*)d_in[2];
    const float* b1 = (const float*)d_in[3];
    const float* W2 = (const float*)d_in[4];
    const float* b2 = (const float*)d_in[5];
    const float* W3 = (const float*)d_in[6];
    const float* b3 = (const float*)d_in[7];
    float* out = (float*)d_out;
    unsigned short* Wp = (unsigned short*)d_ws;   // 3*64*192*2 = 73728 B

    int n = in_sizes[0] / (ND * 12);              // 65536

    repack_w<<<144, 256, 0, stream>>>(W1, W2, W3, Wp);
    dijet_main<<<n / SPB, 256, 0, stream>>>(x, dd, b1, b2, b3, Wp, out);
}

// Round 2
// 421.696 us; speedup vs baseline: 1.0524x; 1.0524x over previous
//
#include <hip/hip_runtime.h>

#define ND 64
#define NPAIR 6

typedef short bf16x8 __attribute__((ext_vector_type(8)));
typedef float floatx4 __attribute__((ext_vector_type(4)));

static constexpr int SPB  = 16;            // samples per block
static constexpr int ROWS = SPB * NPAIR;   // 96 M-rows per block
static constexpr int ASTR = 200;           // halfwords per A row (192 + 8 pad; 400B, 16B-aligned, bank-spread)

__device__ __forceinline__ unsigned short f2bf(float f) {
    unsigned u = __builtin_bit_cast(unsigned, f);
    u += 0x7FFFu + ((u >> 16) & 1u);       // round-to-nearest-even (no NaN inputs)
    return (unsigned short)(u >> 16);
}
__device__ __forceinline__ unsigned f2bf2(float lo, float hi) {
    return (unsigned)f2bf(lo) | ((unsigned)f2bf(hi) << 16);
}

// Repack W1..3 [o][i][k] fp32 -> bf16 B-operand layout P[L][n=o][j], j<128: (i=j>>1,k=j&1), j>=128: (i=j-128,k=2)
__global__ void repack_w(const float* __restrict__ W1, const float* __restrict__ W2,
                         const float* __restrict__ W3, unsigned short* __restrict__ P) {
    int idx = blockIdx.x * 256 + threadIdx.x;
    if (idx >= 3 * 64 * 192) return;
    int j = idx % 192;
    int n = (idx / 192) % 64;
    int L = idx / (192 * 64);
    const float* W = (L == 0) ? W1 : (L == 1) ? W2 : W3;
    float v = (j < 128) ? W[n * 192 + (j >> 1) * 3 + (j & 1)]
                        : W[n * 192 + (j - 128) * 3 + 2];
    P[idx] = f2bf(v);
}

__global__ __launch_bounds__(256, 4) void dijet_main(
    const float* __restrict__ x, const float* __restrict__ d,
    const float* __restrict__ b1, const float* __restrict__ b2,
    const float* __restrict__ b3, const unsigned short* __restrict__ Wp,
    float* __restrict__ out)
{
    // A: [row][j] bf16, j<128 x-part, j>=128 d-part (updated per layer). 38400 B.
    // At the final epilogue A is dead; its space is reused as Ct (96*64 fp32 = 24576 B).
    __shared__ __align__(16) unsigned short A[ROWS * ASTR];
    float* Ct = (float*)A;

    const int t  = threadIdx.x;
    const int b0 = blockIdx.x * SPB;

    // ---- stage x: 16 samples x 768 floats = 3072 float4; coalesced; convert + scatter to A x-part
    {
        const float4* x4 = (const float4*)(x + (size_t)b0 * (ND * 12));
        unsigned* A32 = (unsigned*)A;
        #pragma unroll
        for (int half = 0; half < 2; ++half) {
            float4 v[6];
            #pragma unroll
            for (int m = 0; m < 6; ++m) v[m] = x4[(half * 6 + m) * 256 + t];
            #pragma unroll
            for (int m = 0; m < 6; ++m) {
                int idx = (half * 6 + m) * 256 + t;   // 0..3071
                int b   = idx / 192;                  // 192 float4 per sample
                int rem = idx - b * 192;
                int i   = rem / 3;                    // channel
                int c0  = (rem - i * 3) * 4;          // 0,4,8
                int row0 = b * 6 + (c0 >> 1);         // slot = c/2
                A32[row0 * (ASTR / 2) + i]       = f2bf2(v[m].x, v[m].y);  // j = 2i, 2i+1
                A32[(row0 + 1) * (ASTR / 2) + i] = f2bf2(v[m].z, v[m].w);
            }
        }
    }
    // ---- stage d: 16 samples x 384 floats = 3072 float2; each float2 = same i, slots (s,s+1)
    {
        const float2* d2 = (const float2*)(d + (size_t)b0 * (ND * NPAIR));
        #pragma unroll
        for (int half = 0; half < 2; ++half) {
            float2 v[6];
            #pragma unroll
            for (int m = 0; m < 6; ++m) v[m] = d2[(half * 6 + m) * 256 + t];
            #pragma unroll
            for (int m = 0; m < 6; ++m) {
                int idx = (half * 6 + m) * 256 + t;   // 0..3071
                int e   = idx * 2;
                int b   = e / 384;
                int rem = e - b * 384;
                int i   = rem / 6;
                int s   = rem - i * 6;                // even
                int row = b * 6 + s;
                A[row * ASTR + 128 + i]       = f2bf(v[m].x);
                A[(row + 1) * ASTR + 128 + i] = f2bf(v[m].y);
            }
        }
    }
    __syncthreads();

    const int wave = t >> 6;
    const int lane = t & 63;
    const int mhalf = wave & 1;                // row half (48 rows)
    const int nhalf = wave >> 1;               // col half (32 cols)
    const int l15  = lane & 15;
    const int quad = lane >> 4;

    const int mbase = mhalf * 48;
    const int nbase = nhalf * 32;

    #pragma unroll
    for (int L = 0; L < 3; ++L) {
        const float* bL = (L == 0) ? b1 : (L == 1) ? b2 : b3;
        const unsigned short* WL = Wp + L * (64 * 192);

        // B fragments for this wave's col half: 2 n-tiles x 6 k-steps, from L2-resident packed weights
        bf16x8 Bf[2][6];
        #pragma unroll
        for (int nt = 0; nt < 2; ++nt)
            #pragma unroll
            for (int kk = 0; kk < 6; ++kk)
                Bf[nt][kk] = *(const bf16x8*)(WL + (nbase + nt * 16 + l15) * 192 + kk * 32 + quad * 8);
        float bias0 = bL[nbase + l15];
        float bias1 = bL[nbase + 16 + l15];

        floatx4 acc[3][2] = {};
        #pragma unroll
        for (int kk = 0; kk < 6; ++kk) {
            #pragma unroll
            for (int mt = 0; mt < 3; ++mt) {
                bf16x8 Af = *(const bf16x8*)(A + (mbase + mt * 16 + l15) * ASTR + kk * 32 + quad * 8);
                acc[mt][0] = __builtin_amdgcn_mfma_f32_16x16x32_bf16(Af, Bf[0][kk], acc[mt][0], 0, 0, 0);
                acc[mt][1] = __builtin_amdgcn_mfma_f32_16x16x32_bf16(Af, Bf[1][kk], acc[mt][1], 0, 0, 0);
            }
        }

        if (L < 2) {
            __syncthreads();   // everyone done reading old d-part
            #pragma unroll
            for (int mt = 0; mt < 3; ++mt) {
                #pragma unroll
                for (int nt = 0; nt < 2; ++nt) {
                    float bias = nt ? bias1 : bias0;
                    int o = nbase + nt * 16 + l15;
                    #pragma unroll
                    for (int r = 0; r < 4; ++r) {
                        int row = mbase + mt * 16 + quad * 4 + r;   // C/D: col=lane&15, row=quad*4+reg
                        float v = acc[mt][nt][r] + bias;
                        v = v > 0.f ? v : 0.f;
                        A[row * ASTR + 128 + o] = f2bf(v);
                    }
                }
            }
            __syncthreads();   // new d visible before next layer's reads
        } else {
            __syncthreads();   // all waves done reading A; safe to overlay Ct
            // transpose C (fp32, + bias) into [b][o*6+s] layout over A's storage
            #pragma unroll
            for (int mt = 0; mt < 3; ++mt) {
                #pragma unroll
                for (int nt = 0; nt < 2; ++nt) {
                    float bias = nt ? bias1 : bias0;
                    int o = nbase + nt * 16 + l15;
                    #pragma unroll
                    for (int r = 0; r < 4; ++r) {
                        int row = mbase + mt * 16 + quad * 4 + r;
                        int bl  = row / 6;
                        int s   = row - bl * 6;
                        Ct[bl * (ND * NPAIR) + o * NPAIR + s] = acc[mt][nt][r] + bias;
                    }
                }
            }
            __syncthreads();
            // coalesced: read Ct + residual d (same flat layout as out), relu, store
            const float4* dres4 = (const float4*)(d + (size_t)b0 * (ND * NPAIR));
            float4*       out4  = (float4*)(out + (size_t)b0 * (ND * NPAIR));
            const float4* Ct4   = (const float4*)Ct;
            #pragma unroll
            for (int m = 0; m < 6; ++m) {
                int idx = m * 256 + t;               // 0..1535
                float4 c = Ct4[idx];
                float4 dv = dres4[idx];
                float4 r;
                r.x = c.x + dv.x; r.x = r.x > 0.f ? r.x : 0.f;
                r.y = c.y + dv.y; r.y = r.y > 0.f ? r.y : 0.f;
                r.z = c.z + dv.z; r.z = r.z > 0.f ? r.z : 0.f;
                r.w = c.w + dv.w; r.w = r.w > 0.f ? r.w : 0.f;
                out4[idx] = r;
            }
        }
    }
}

extern "C" void kernel_launch(void* const* d_in, const int* in_sizes, int n_in,
                              void* d_out, int out_size, void* d_ws, size_t ws_size,
                              hipStream_t stream)
{
    const float* x  = (const float*)d_in[0];
    const float* dd = (const float*)d_in[1];
    const float* W1 = (const float*)d_in[2];
    const float* b1 = (const float*)d_in[3];
    const float* W2 = (const float*)d_in[4];
    const float* b2 = (const float*)d_in[5];
    const float* W3 = (const float*)d_in[6];
    const float* b3 = (const float*)d_in[7];
    float* out = (float*)d_out;
    unsigned short* Wp = (unsigned short*)d_ws;   // 3*64*192*2 = 73728 B

    int n = in_sizes[0] / (ND * 12);              // 65536

    repack_w<<<144, 256, 0, stream>>>(W1, W2, W3, Wp);
    dijet_main<<<n / SPB, 256, 0, stream>>>(x, dd, b1, b2, b3, Wp, out);
}

// Round 3
// 390.714 us; speedup vs baseline: 1.1359x; 1.0793x over previous
//
#include <hip/hip_runtime.h>

#define ND 64
#define NPAIR 6

typedef short bf16x8 __attribute__((ext_vector_type(8)));
typedef float floatx4 __attribute__((ext_vector_type(4)));

static constexpr int SPB  = 8;             // samples per block
static constexpr int ROWS = SPB * NPAIR;   // 48 M-rows per block
static constexpr int ASTR = 200;           // halfwords per A row (192 + 8 pad; 400B, 16B-aligned, bank-spread)

__device__ __forceinline__ unsigned short f2bf(float f) {
    unsigned u = __builtin_bit_cast(unsigned, f);
    u += 0x7FFFu + ((u >> 16) & 1u);       // round-to-nearest-even (no NaN inputs)
    return (unsigned short)(u >> 16);
}
__device__ __forceinline__ unsigned f2bf2(float lo, float hi) {
    return (unsigned)f2bf(lo) | ((unsigned)f2bf(hi) << 16);
}

// Repack W1..3 [o][i][k] fp32 -> bf16 B-operand layout P[L][n=o][j], j<128: (i=j>>1,k=j&1), j>=128: (i=j-128,k=2)
__global__ void repack_w(const float* __restrict__ W1, const float* __restrict__ W2,
                         const float* __restrict__ W3, unsigned short* __restrict__ P) {
    int idx = blockIdx.x * 256 + threadIdx.x;
    if (idx >= 3 * 64 * 192) return;
    int j = idx % 192;
    int n = (idx / 192) % 64;
    int L = idx / (192 * 64);
    const float* W = (L == 0) ? W1 : (L == 1) ? W2 : W3;
    float v = (j < 128) ? W[n * 192 + (j >> 1) * 3 + (j & 1)]
                        : W[n * 192 + (j - 128) * 3 + 2];
    P[idx] = f2bf(v);
}

__global__ __launch_bounds__(256, 7) void dijet_main(
    const float* __restrict__ x, const float* __restrict__ d,
    const float* __restrict__ b1, const float* __restrict__ b2,
    const float* __restrict__ b3, const unsigned short* __restrict__ Wp,
    float* __restrict__ out)
{
    // A: [row][j] bf16, j<128 x-part, j>=128 d-part (updated per layer). 19200 B.
    // At the final epilogue A is dead; reused as Ct (48*64 fp32 = 12288 B).
    __shared__ __align__(16) unsigned short A[ROWS * ASTR];
    float* Ct = (float*)A;

    const int t  = threadIdx.x;
    const int b0 = blockIdx.x * SPB;

    // ---- stage d first (kept in registers for the residual): 8 samples x 384 floats = 1536 float2
    float2 dres[6];
    {
        const float2* d2 = (const float2*)(d + (size_t)b0 * (ND * NPAIR));
        #pragma unroll
        for (int m = 0; m < 6; ++m) dres[m] = d2[m * 256 + t];
    }
    // ---- stage x: 8 samples x 768 floats = 1536 float4; coalesced; convert + scatter to A x-part
    {
        const float4* x4 = (const float4*)(x + (size_t)b0 * (ND * 12));
        float4 v[6];
        #pragma unroll
        for (int m = 0; m < 6; ++m) v[m] = x4[m * 256 + t];
        unsigned* A32 = (unsigned*)A;
        #pragma unroll
        for (int m = 0; m < 6; ++m) {
            int idx = m * 256 + t;                // 0..1535
            int b   = idx / 192;                  // 192 float4 per sample
            int rem = idx - b * 192;
            int i   = rem / 3;                    // channel
            int c0  = (rem - i * 3) * 4;          // 0,4,8
            int row0 = b * 6 + (c0 >> 1);         // slot = c/2
            A32[row0 * (ASTR / 2) + i]       = f2bf2(v[m].x, v[m].y);  // j = 2i, 2i+1
            A32[(row0 + 1) * (ASTR / 2) + i] = f2bf2(v[m].z, v[m].w);
        }
    }
    // ---- scatter d to A d-part: each float2 = same i, slots (s,s+1)
    {
        #pragma unroll
        for (int m = 0; m < 6; ++m) {
            int idx = m * 256 + t;                // 0..1535
            int e   = idx * 2;
            int b   = e / 384;
            int rem = e - b * 384;
            int i   = rem / 6;
            int s   = rem - i * 6;                // even
            int row = b * 6 + s;
            A[row * ASTR + 128 + i]       = f2bf(dres[m].x);
            A[(row + 1) * ASTR + 128 + i] = f2bf(dres[m].y);
        }
    }
    __syncthreads();

    const int wave = t >> 6;
    const int lane = t & 63;
    const int l15  = lane & 15;
    const int quad = lane >> 4;
    const int nbase = wave * 16;                  // each wave: all 48 rows x 16 cols

    #pragma unroll
    for (int L = 0; L < 3; ++L) {
        const float* bL = (L == 0) ? b1 : (L == 1) ? b2 : b3;
        const unsigned short* WL = Wp + L * (64 * 192);

        // B fragments for this wave's 16 output cols: 6 k-steps, from L2-resident packed weights
        bf16x8 Bf[6];
        #pragma unroll
        for (int kk = 0; kk < 6; ++kk)
            Bf[kk] = *(const bf16x8*)(WL + (nbase + l15) * 192 + kk * 32 + quad * 8);
        float bias = bL[nbase + l15];

        floatx4 acc[3] = {};
        #pragma unroll
        for (int kk = 0; kk < 6; ++kk) {
            #pragma unroll
            for (int mt = 0; mt < 3; ++mt) {
                bf16x8 Af = *(const bf16x8*)(A + (mt * 16 + l15) * ASTR + kk * 32 + quad * 8);
                acc[mt] = __builtin_amdgcn_mfma_f32_16x16x32_bf16(Af, Bf[kk], acc[mt], 0, 0, 0);
            }
        }

        const int o = nbase + l15;
        if (L < 2) {
            __syncthreads();   // everyone done reading old d-part
            #pragma unroll
            for (int mt = 0; mt < 3; ++mt) {
                #pragma unroll
                for (int r = 0; r < 4; ++r) {
                    int row = mt * 16 + quad * 4 + r;   // C/D: col=lane&15, row=quad*4+reg
                    float v = acc[mt][r] + bias;
                    v = v > 0.f ? v : 0.f;
                    A[row * ASTR + 128 + o] = f2bf(v);
                }
            }
            __syncthreads();   // new d visible before next layer's reads
        } else {
            __syncthreads();   // all waves done reading A; safe to overlay Ct
            // transpose C (fp32, + bias) into [b][o*6+s] layout over A's storage
            #pragma unroll
            for (int mt = 0; mt < 3; ++mt) {
                #pragma unroll
                for (int r = 0; r < 4; ++r) {
                    int row = mt * 16 + quad * 4 + r;
                    int bl  = row / 6;
                    int s   = row - bl * 6;
                    Ct[bl * (ND * NPAIR) + o * NPAIR + s] = acc[mt][r] + bias;
                }
            }
            __syncthreads();
            // coalesced float2 stores fused with register-resident residual
            float2* out2 = (float2*)(out + (size_t)b0 * (ND * NPAIR));
            const float2* Ct2 = (const float2*)Ct;
            #pragma unroll
            for (int m = 0; m < 6; ++m) {
                int idx = m * 256 + t;               // 0..1535
                float2 c = Ct2[idx];
                float2 r;
                r.x = c.x + dres[m].x; r.x = r.x > 0.f ? r.x : 0.f;
                r.y = c.y + dres[m].y; r.y = r.y > 0.f ? r.y : 0.f;
                out2[idx] = r;
            }
        }
    }
}

extern "C" void kernel_launch(void* const* d_in, const int* in_sizes, int n_in,
                              void* d_out, int out_size, void* d_ws, size_t ws_size,
                              hipStream_t stream)
{
    const float* x  = (const float*)d_in[0];
    const float* dd = (const float*)d_in[1];
    const float* W1 = (const float*)d_in[2];
    const float* b1 = (const float*)d_in[3];
    const float* W2 = (const float*)d_in[4];
    const float* b2 = (const float*)d_in[5];
    const float* W3 = (const float*)d_in[6];
    const float* b3 = (const float*)d_in[7];
    float* out = (float*)d_out;
    unsigned short* Wp = (unsigned short*)d_ws;   // 3*64*192*2 = 73728 B

    int n = in_sizes[0] / (ND * 12);              // 65536

    repack_w<<<144, 256, 0, stream>>>(W1, W2, W3, Wp);
    dijet_main<<<n / SPB, 256, 0, stream>>>(x, dd, b1, b2, b3, Wp, out);
}